// Round 1
// baseline (4209.484 us; speedup 1.0000x reference)
//
#include <hip/hip_runtime.h>

// ---- problem dims ----
#define NN 20000
#define NE 640000
#define FF 128
#define H1 64
#define H2 32
#define RR 65
#define BQ 4096
#define NR (NN*RR)

// ---- small scratch block offsets (ints within sm[1024]) ----
#define SM_HIST_A 0
#define SM_START_A 128
#define SM_CUR_A 256
#define SM_HIST_B 384
#define SM_START_B 512
#define SM_CUR_B 640
#define SM_HACC 768   // 32 floats
#define SM_V 832      // 32 floats

#define CPB1 12       // chunks (blocks) per relation, layer 1
#define CPB2 12       // layer 2

// ===================== histogram: cnt[(dst,rel)] + per-type counts =====================
__global__ __launch_bounds__(256) void k_hist(
    const int* __restrict__ ei, const int* __restrict__ etA, const int* __restrict__ etB,
    int* __restrict__ cntA, int* __restrict__ cntB, int* __restrict__ sm) {
  __shared__ int lh[2 * RR];
  int tid = threadIdx.x;
  for (int i = tid; i < 2 * RR; i += blockDim.x) lh[i] = 0;
  __syncthreads();
  int e = blockIdx.x * blockDim.x + tid;
  if (e < NE) {
    int dst = ei[NE + e];
    int ta = etA[e], tb = etB[e];
    atomicAdd(&cntA[dst * RR + ta], 1);
    atomicAdd(&cntB[dst * RR + tb], 1);
    atomicAdd(&lh[ta], 1);
    atomicAdd(&lh[RR + tb], 1);
  }
  __syncthreads();
  for (int i = tid; i < 2 * RR; i += blockDim.x) {
    int c = lh[i];
    if (c) atomicAdd(&sm[(i < RR) ? (SM_HIST_A + i) : (SM_HIST_B + (i - RR))], c);
  }
}

// ===================== exclusive prefix over 65 bins (A by wave0 lane0, B by wave1 lane0) ===
__global__ __launch_bounds__(128) void k_prefix(int* __restrict__ sm) {
  int w = threadIdx.x >> 6;
  if ((threadIdx.x & 63) == 0 && w < 2) {
    int hb = w ? SM_HIST_B : SM_HIST_A;
    int sb = w ? SM_START_B : SM_START_A;
    int cb = w ? SM_CUR_B : SM_CUR_A;
    int h[RR];
#pragma unroll
    for (int r = 0; r < RR; ++r) h[r] = sm[hb + r];
    int s = 0;
#pragma unroll
    for (int r = 0; r < RR; ++r) { sm[sb + r] = s; sm[cb + r] = s; s += h[r]; }
  }
}

// ===================== counting-sort scatter (block-aggregated, rank from DS atomic) ========
__global__ __launch_bounds__(256) void k_scatter(
    const int* __restrict__ etA, const int* __restrict__ etB,
    int* __restrict__ sm, int* __restrict__ ordA, int* __restrict__ ordB) {
  __shared__ int lhA[RR], lbA[RR], lhB[RR], lbB[RR];
  int tid = threadIdx.x;
  for (int i = tid; i < RR; i += blockDim.x) { lhA[i] = 0; lhB[i] = 0; }
  __syncthreads();
  int e = blockIdx.x * blockDim.x + tid;
  int ta = 0, tb = 0, ra = 0, rb = 0;
  bool valid = (e < NE);
  if (valid) {
    ta = etA[e]; tb = etB[e];
    ra = atomicAdd(&lhA[ta], 1);
    rb = atomicAdd(&lhB[tb], 1);
  }
  __syncthreads();
  for (int i = tid; i < RR; i += blockDim.x) {
    if (lhA[i]) lbA[i] = atomicAdd(&sm[SM_CUR_A + i], lhA[i]);
    if (lhB[i]) lbB[i] = atomicAdd(&sm[SM_CUR_B + i], lhB[i]);
  }
  __syncthreads();
  if (valid) { ordA[lbA[ta] + ra] = e; ordB[lbB[tb] + rb] = e; }
}

// ===================== counts -> 1/cnt (float, in place) =====================
__global__ __launch_bounds__(256) void k_inv(int* __restrict__ cntA, int* __restrict__ cntB) {
  int i = blockIdx.x * blockDim.x + threadIdx.x;
  if (i < NR) {
    int c = cntA[i]; ((float*)cntA)[i] = (c > 0) ? 1.0f / (float)c : 0.0f;
    c = cntB[i];     ((float*)cntB)[i] = (c > 0) ? 1.0f / (float)c : 0.0f;
  }
}

// ===================== layer-1 root term: one wave per node row, both inputs ================
// yo = x_o@rt + b ; yaa = same (pass-3 shares x_o root term) ; ya = x_a@rt + b
__global__ __launch_bounds__(256) void k_root1(
    const float* __restrict__ xo, const float* __restrict__ xa,
    const float* __restrict__ rt, const float* __restrict__ b,
    float* __restrict__ yo, float* __restrict__ yaa, float* __restrict__ ya) {
  int lane = threadIdx.x & 63;
  int n = (blockIdx.x * blockDim.x + threadIdx.x) >> 6;
  if (n >= NN) return;
  const float4* xo4 = (const float4*)(xo + (size_t)n * FF);
  const float4* xa4 = (const float4*)(xa + (size_t)n * FF);
  float so = b[lane], sa = so;
#pragma unroll
  for (int j = 0; j < FF / 4; ++j) {
    float vo[4], va[4];
    *(float4*)vo = xo4[j];
    *(float4*)va = xa4[j];
#pragma unroll
    for (int t = 0; t < 4; ++t) {
      float wv = rt[(4 * j + t) * H1 + lane];
      so = fmaf(vo[t], wv, so);
      sa = fmaf(va[t], wv, sa);
    }
  }
  yo[(size_t)n * H1 + lane] = so;
  yaa[(size_t)n * H1 + lane] = so;
  ya[(size_t)n * H1 + lane] = sa;
}

// ===================== layer-1 edge transform+scatter ===============================
// One relation per CPB1 blocks; W_r staged in 128 VGPRs/lane (lane = out col).
// Per edge: y[lane] = sum_k x[src][k]*W[k][lane]; atomicAdd(y*inv) into out[dst].
template <int NIN>
__global__ __launch_bounds__(256, 2) void k_edge1(
    const int* __restrict__ ei, const int* __restrict__ ord,
    const int* __restrict__ sm, int startOff, int histOff,
    const float* __restrict__ invc, const float* __restrict__ W1,
    const float* __restrict__ xo, const float* __restrict__ xa,
    float* __restrict__ yo, float* __restrict__ ya) {
  const int r = blockIdx.x / CPB1;
  const int chunk = blockIdx.x - r * CPB1;
  const int lane = threadIdx.x & 63;
  const int wv = chunk * 4 + (threadIdx.x >> 6);
  const int stride = CPB1 * 4;

  float w[FF];
  {
    const float* Wr = W1 + (size_t)r * (FF * H1) + lane;
#pragma unroll
    for (int k = 0; k < FF; ++k) w[k] = Wr[(size_t)k * H1];
  }
  const int s0 = sm[startOff + r];
  const int cnt = sm[histOff + r];

  int p = wv;
  int e = 0, src = 0, dst = 0; float inv = 0.f;
  if (p < cnt) {
    e = ord[s0 + p]; src = ei[e]; dst = ei[NE + e];
    inv = invc[dst * RR + r];
  }
  while (p < cnt) {
    const int pn = p + stride;
    int en = 0, srcn = 0, dstn = 0; float invn = 0.f;
    if (pn < cnt) {                          // prefetch next edge's metadata under the FMAs
      en = ord[s0 + pn]; srcn = ei[en]; dstn = ei[NE + en];
      invn = invc[dstn * RR + r];
    }
    const float4* xo4 = (const float4*)(xo + (size_t)src * FF);
    const float4* xa4 = (NIN == 2) ? (const float4*)(xa + (size_t)src * FF) : nullptr;
    float acco = 0.f, acca = 0.f;
#pragma unroll
    for (int j = 0; j < FF / 4; ++j) {
      float vo[4];
      *(float4*)vo = xo4[j];
#pragma unroll
      for (int t = 0; t < 4; ++t) acco = fmaf(vo[t], w[4 * j + t], acco);
      if constexpr (NIN == 2) {
        float va[4];
        *(float4*)va = xa4[j];
#pragma unroll
        for (int t = 0; t < 4; ++t) acca = fmaf(va[t], w[4 * j + t], acca);
      }
    }
    unsafeAtomicAdd(&yo[(size_t)dst * H1 + lane], acco * inv);
    if constexpr (NIN == 2) unsafeAtomicAdd(&ya[(size_t)dst * H1 + lane], acca * inv);
    p = pn; e = en; src = srcn; dst = dstn; inv = invn;
  }
}

// ===================== relu over contiguous x1 buffers =====================
__global__ __launch_bounds__(256) void k_relu4(float4* __restrict__ a, int n4) {
  int i = blockIdx.x * blockDim.x + threadIdx.x;
  if (i < n4) {
    float4 v = a[i];
    v.x = fmaxf(v.x, 0.f); v.y = fmaxf(v.y, 0.f);
    v.z = fmaxf(v.z, 0.f); v.w = fmaxf(v.w, 0.f);
    a[i] = v;
  }
}

// ===================== layer-2 root term =====================
__global__ __launch_bounds__(256) void k_root2(
    const float* __restrict__ x1, const float* __restrict__ rt,
    const float* __restrict__ b, float* __restrict__ y) {
  int i = blockIdx.x * blockDim.x + threadIdx.x;
  if (i >= NN * H2) return;
  int o = i & (H2 - 1);
  int n = i >> 5;
  const float4* x4 = (const float4*)(x1 + (size_t)n * H1);
  float s = b[o];
#pragma unroll
  for (int j = 0; j < H1 / 4; ++j) {
    float v[4];
    *(float4*)v = x4[j];
#pragma unroll
    for (int t = 0; t < 4; ++t) s = fmaf(v[t], rt[(4 * j + t) * H2 + o], s);
  }
  y[i] = s;
}

// ===================== layer-2 edge transform+scatter ===============================
// lane = (half = lane>>5 selects k-range, o = lane&31); 32 W regs/lane; shfl_xor(32) combines.
template <int NIN>
__global__ __launch_bounds__(256, 4) void k_edge2(
    const int* __restrict__ ei, const int* __restrict__ ord,
    const int* __restrict__ sm, int startOff, int histOff,
    const float* __restrict__ invc, const float* __restrict__ W2,
    const float* __restrict__ xo, const float* __restrict__ xa,
    float* __restrict__ yo, float* __restrict__ ya) {
  const int r = blockIdx.x / CPB2;
  const int chunk = blockIdx.x - r * CPB2;
  const int lane = threadIdx.x & 63;
  const int half = lane >> 5;
  const int o = lane & 31;
  const int wv = chunk * 4 + (threadIdx.x >> 6);
  const int stride = CPB2 * 4;

  float w[H1 / 2];
  {
    const float* Wr = W2 + (size_t)r * (H1 * H2) + (half * (H1 / 2)) * H2 + o;
#pragma unroll
    for (int j = 0; j < H1 / 2; ++j) w[j] = Wr[j * H2];
  }
  const int s0 = sm[startOff + r];
  const int cnt = sm[histOff + r];

  int p = wv;
  int e = 0, src = 0, dst = 0; float inv = 0.f;
  if (p < cnt) {
    e = ord[s0 + p]; src = ei[e]; dst = ei[NE + e];
    inv = invc[dst * RR + r];
  }
  while (p < cnt) {
    const int pn = p + stride;
    int en = 0, srcn = 0, dstn = 0; float invn = 0.f;
    if (pn < cnt) {
      en = ord[s0 + pn]; srcn = ei[en]; dstn = ei[NE + en];
      invn = invc[dstn * RR + r];
    }
    const float4* xo4 = (const float4*)(xo + (size_t)src * H1 + half * (H1 / 2));
    const float4* xa4 = (NIN == 2) ? (const float4*)(xa + (size_t)src * H1 + half * (H1 / 2)) : nullptr;
    float acco = 0.f, acca = 0.f;
#pragma unroll
    for (int j = 0; j < H1 / 8; ++j) {
      float vo[4];
      *(float4*)vo = xo4[j];
#pragma unroll
      for (int t = 0; t < 4; ++t) acco = fmaf(vo[t], w[4 * j + t], acco);
      if constexpr (NIN == 2) {
        float va[4];
        *(float4*)va = xa4[j];
#pragma unroll
        for (int t = 0; t < 4; ++t) acca = fmaf(va[t], w[4 * j + t], acca);
      }
    }
    acco += __shfl_xor(acco, 32);
    if constexpr (NIN == 2) acca += __shfl_xor(acca, 32);
    if (half == 0) {
      unsafeAtomicAdd(&yo[(size_t)dst * H2 + o], acco * inv);
      if constexpr (NIN == 2) unsafeAtomicAdd(&ya[(size_t)dst * H2 + o], acca * inv);
    }
    p = pn; e = en; src = srcn; dst = dstn; inv = invn;
  }
}

// ===================== column sum of x2_o -> hacc[32] =====================
__global__ __launch_bounds__(256) void k_colsum(const float* __restrict__ x2o,
                                                float* __restrict__ hacc) {
  int tid = threadIdx.x;
  int col = tid & 31;
  int rgrp = blockIdx.x * (blockDim.x >> 5) + (tid >> 5);
  int nth = gridDim.x * (blockDim.x >> 5);
  float s = 0.f;
  for (int n = rgrp; n < NN; n += nth) s += x2o[(size_t)n * H2 + col];
  unsafeAtomicAdd(&hacc[col], s);
}

// ===================== h_os = sigmoid(mean); v = disc_w @ h_os =====================
__global__ __launch_bounds__(64) void k_disc(const float* __restrict__ hacc,
                                             const float* __restrict__ dw,
                                             float* __restrict__ vout) {
  __shared__ float hos[H2];
  int t = threadIdx.x;
  if (t < H2) hos[t] = 1.0f / (1.0f + expf(-hacc[t] / (float)NN));
  __syncthreads();
  if (t < H2) {
    float s = 0.f;
#pragma unroll
    for (int k = 0; k < H2; ++k) s = fmaf(dw[t * H2 + k], hos[k], s);
    vout[t] = s;
  }
}

// ===================== ret_os / ret_os_a (col0 shared) =====================
__global__ __launch_bounds__(256) void k_ret(
    const float* __restrict__ x2o, const float* __restrict__ x2oa, const float* __restrict__ x2oaa,
    const float* __restrict__ v, const float* __restrict__ db,
    float* __restrict__ ros, float* __restrict__ rosa) {
  int n = blockIdx.x * blockDim.x + threadIdx.x;
  if (n >= NN) return;
  const float4* a4 = (const float4*)(x2o + (size_t)n * H2);
  const float4* b4 = (const float4*)(x2oa + (size_t)n * H2);
  const float4* c4 = (const float4*)(x2oaa + (size_t)n * H2);
  const float4* v4 = (const float4*)v;
  float r0 = 0.f, r1 = 0.f, r2 = 0.f;
#pragma unroll
  for (int j = 0; j < H2 / 4; ++j) {
    float va[4], vb[4], vc[4], vv[4];
    *(float4*)va = a4[j]; *(float4*)vb = b4[j]; *(float4*)vc = c4[j]; *(float4*)vv = v4[j];
#pragma unroll
    for (int t = 0; t < 4; ++t) {
      r0 = fmaf(va[t], vv[t], r0);
      r1 = fmaf(vb[t], vv[t], r1);
      r2 = fmaf(vc[t], vv[t], r2);
    }
  }
  float bb = db[0];
  ros[n * 2] = r0 + bb;  ros[n * 2 + 1] = r1 + bb;
  rosa[n * 2] = r0 + bb; rosa[n * 2 + 1] = r2 + bb;
}

// ===================== classifier: log[b][r] =====================
__global__ __launch_bounds__(128) void k_cls(
    const int* __restrict__ idx, const float* __restrict__ x1o, const float* __restrict__ x2o,
    const float* __restrict__ attt, const float* __restrict__ cw, const float* __restrict__ cb,
    float* __restrict__ lg) {
  int b = blockIdx.x;
  int r = threadIdx.x;
  if (r >= RR) return;
  int i1 = idx[b], i2 = idx[BQ + b];
  float a0 = attt[0], a1 = attt[1];
  float acc = cb[r];
  const float4* q1 = (const float4*)(x1o + (size_t)i1 * H1);
  const float4* q2 = (const float4*)(x2o + (size_t)i1 * H2);
  const float4* q3 = (const float4*)(x1o + (size_t)i2 * H1);
  const float4* q4 = (const float4*)(x2o + (size_t)i2 * H2);
#pragma unroll
  for (int j = 0; j < H1 / 4; ++j) {
    float v[4]; *(float4*)v = q1[j];
#pragma unroll
    for (int t = 0; t < 4; ++t) acc = fmaf(a0 * v[t], cw[(4 * j + t) * RR + r], acc);
  }
#pragma unroll
  for (int j = 0; j < H2 / 4; ++j) {
    float v[4]; *(float4*)v = q2[j];
#pragma unroll
    for (int t = 0; t < 4; ++t) acc = fmaf(a1 * v[t], cw[(H1 + 4 * j + t) * RR + r], acc);
  }
#pragma unroll
  for (int j = 0; j < H1 / 4; ++j) {
    float v[4]; *(float4*)v = q3[j];
#pragma unroll
    for (int t = 0; t < 4; ++t) acc = fmaf(a0 * v[t], cw[(96 + 4 * j + t) * RR + r], acc);
  }
#pragma unroll
  for (int j = 0; j < H2 / 4; ++j) {
    float v[4]; *(float4*)v = q4[j];
#pragma unroll
    for (int t = 0; t < 4; ++t) acc = fmaf(a1 * v[t], cw[(96 + H1 + 4 * j + t) * RR + r], acc);
  }
  lg[(size_t)b * RR + r] = acc;
}

// ===================== launch =====================
extern "C" void kernel_launch(void* const* d_in, const int* in_sizes, int n_in,
                              void* d_out, int out_size, void* d_ws, size_t ws_size,
                              hipStream_t stream) {
  const float* x_o  = (const float*)d_in[0];
  const float* x_a  = (const float*)d_in[1];
  const int*   ei   = (const int*)d_in[2];
  const int*   etA  = (const int*)d_in[3];
  const int*   etB  = (const int*)d_in[4];
  const int*   idx  = (const int*)d_in[5];
  const float* W1   = (const float*)d_in[6];
  const float* rt1  = (const float*)d_in[7];
  const float* b1   = (const float*)d_in[8];
  const float* W2   = (const float*)d_in[9];
  const float* rt2  = (const float*)d_in[10];
  const float* b2   = (const float*)d_in[11];
  const float* attt = (const float*)d_in[12];
  const float* dw   = (const float*)d_in[13];
  const float* db   = (const float*)d_in[14];
  const float* cw   = (const float*)d_in[15];
  const float* cb   = (const float*)d_in[16];

  // workspace layout (4B elements), each region 256-elem aligned
  const size_t NRp = 1300224;                  // NR=1,300,000 padded
  int* wsI  = (int*)d_ws;
  int* cntA = wsI;                             // NRp ints -> becomes float inv
  int* cntB = wsI + NRp;                       // NRp ints -> float inv
  int* sm   = wsI + 2 * NRp;                   // 1024 ints (hist/start/cur/hacc/v)
  int* ordA = sm + 1024;                       // NE
  int* ordB = ordA + NE;                       // NE
  float* x1o   = (float*)(ordB + NE);          // NN*H1  (these three contiguous for relu)
  float* x1a   = x1o + (size_t)NN * H1;
  float* x1aa  = x1a + (size_t)NN * H1;
  float* x2oa  = x1aa + (size_t)NN * H1;       // NN*H2
  float* x2oaa = x2oa + (size_t)NN * H2;       // NN*H2
  float* smF   = (float*)sm;
  float* hacc  = smF + SM_HACC;
  float* vbuf  = smF + SM_V;

  float* outF   = (float*)d_out;
  float* o_log  = outF;                        // 4096*65
  float* o_ros  = outF + (size_t)BQ * RR;      // 20000*2
  float* o_rosa = o_ros + (size_t)NN * 2;      // 20000*2
  float* o_x2o  = o_rosa + (size_t)NN * 2;     // 20000*32 (x2_o lives directly in d_out)

  hipMemsetAsync(wsI, 0, (2 * NRp + 1024) * sizeof(int), stream);

  k_hist<<<(NE + 255) / 256, 256, 0, stream>>>(ei, etA, etB, cntA, cntB, sm);
  k_prefix<<<1, 128, 0, stream>>>(sm);
  k_scatter<<<(NE + 255) / 256, 256, 0, stream>>>(etA, etB, sm, ordA, ordB);
  k_inv<<<(NR + 255) / 256, 256, 0, stream>>>(cntA, cntB);

  k_root1<<<(NN * H1) / 256, 256, 0, stream>>>(x_o, x_a, rt1, b1, x1o, x1aa, x1a);
  k_edge1<2><<<RR * CPB1, 256, 0, stream>>>(ei, ordA, sm, SM_START_A, SM_HIST_A,
                                            (const float*)cntA, W1, x_o, x_a, x1o, x1a);
  k_edge1<1><<<RR * CPB1, 256, 0, stream>>>(ei, ordB, sm, SM_START_B, SM_HIST_B,
                                            (const float*)cntB, W1, x_o, nullptr, x1aa, nullptr);
  k_relu4<<<(3 * NN * H1 / 4 + 255) / 256, 256, 0, stream>>>((float4*)x1o, 3 * NN * H1 / 4);

  k_root2<<<(NN * H2 + 255) / 256, 256, 0, stream>>>(x1o, rt2, b2, o_x2o);
  k_root2<<<(NN * H2 + 255) / 256, 256, 0, stream>>>(x1a, rt2, b2, x2oa);
  k_root2<<<(NN * H2 + 255) / 256, 256, 0, stream>>>(x1aa, rt2, b2, x2oaa);
  k_edge2<2><<<RR * CPB2, 256, 0, stream>>>(ei, ordA, sm, SM_START_A, SM_HIST_A,
                                            (const float*)cntA, W2, x1o, x1a, o_x2o, x2oa);
  k_edge2<1><<<RR * CPB2, 256, 0, stream>>>(ei, ordB, sm, SM_START_B, SM_HIST_B,
                                            (const float*)cntB, W2, x1aa, nullptr, x2oaa, nullptr);

  k_colsum<<<128, 256, 0, stream>>>(o_x2o, hacc);
  k_disc<<<1, 64, 0, stream>>>(hacc, dw, vbuf);
  k_ret<<<(NN + 255) / 256, 256, 0, stream>>>(o_x2o, x2oa, x2oaa, vbuf, db, o_ros, o_rosa);
  k_cls<<<BQ, 128, 0, stream>>>(idx, x1o, o_x2o, attt, cw, cb, o_log);
}